// Round 1
// 418.367 us; speedup vs baseline: 1.3409x; 1.3409x over previous
//
#include <hip/hip_runtime.h>
#include <math.h>

// -----------------------------------------------------------------------------
// DFSPH divergence-solve, block-aggregated binning + sort-based reduce.
//   pre:    per-particle 32B {p, r=m/aa, aa, aa^2/m | vx,vy,ax,ay}; zero cursors.
//   bin:    2048 edges/block, PURE STREAM (no gathers). Rank per-bucket in LDS,
//           wave0 scans bucket counts, records counting-sorted by bucket into
//           32KB LDS, then written out wave-linear so bucket runs become
//           full-sector coalesced stores (kills the ~130MB/chunk write-allocate
//           RMW fetch seen in rocprof). ONE 16B record/edge:
//           {jli=(j<<9)|li, gx, gy, gidx} -- j-side physics deferred to reduce.
//   reduce: per 512-record tile: DMA stage (8KB) -> read record to regs +
//           issue pre2[j] gather (8MB table, L2/L3-resident; latency hides
//           under hist+scan) -> hist (1 int atomic/record) -> wave0 scan ->
//           scatter expands to full 32B computed record {c0,c1,c2,r|pj,q5,q6}
//           in sorted[] -> serial register accumulate per particle (no float
//           atomics). i-side v/a corrections applied once at slice-write.
//   fin:    sum SLICES=8 slices, alpha, write [N,5].
// 16B records let nchunk drop 2->1 (cap*512*16 = 144MB fits prior 149MB budget).
// Fallback (tiny ws): direct global float atomics.
// -----------------------------------------------------------------------------

#define PB        512
#define PB_SHIFT  9
#define SLICES    8
#define CSTRIDE   16      // ints per cursor -> 64B, one cacheline each
#define BIN_EPT   8       // edges per thread in bin
#define BIN_EDGES (256 * BIN_EPT)
#define TILE      512     // records staged per reduce tile (8 KB LDS)

typedef float v2f __attribute__((ext_vector_type(2)));

__device__ __forceinline__ void gload_lds16(const float4* g, float4* l) {
    __builtin_amdgcn_global_load_lds(
        (const __attribute__((address_space(1))) void*)g,
        (__attribute__((address_space(3))) void*)l, 16, 0, 0);
}

static inline size_t align256(size_t x) { return (x + 255) & ~(size_t)255; }

__global__ __launch_bounds__(256) void pre_kernel(
    const float*  __restrict__ area,
    const float*  __restrict__ actualArea,
    const float*  __restrict__ restDensity,
    const float*  __restrict__ density,
    const float*  __restrict__ pressure2,
    const float2* __restrict__ vel,
    const float2* __restrict__ accel,
    float4* __restrict__ pre2,
    int*    __restrict__ cursor, int ncursor,
    float*  __restrict__ accz, int nacc,
    int n) {
    int t = blockIdx.x * blockDim.x + threadIdx.x;
    if (t < ncursor) cursor[t] = 0;
    for (int k = t; k < nacc; k += gridDim.x * blockDim.x) accz[k] = 0.f;
    if (t >= n) return;
    float m  = area[t] * restDensity[t];
    float dr = density[t] * restDensity[t];
    float p  = pressure2[t] / (dr * dr);
    float aa = actualArea[t];
    float2 v  = vel[t];
    float2 ac = accel[t];
    pre2[2 * (size_t)t]     = make_float4(p, m / aa, aa, aa * aa / m);
    pre2[2 * (size_t)t + 1] = make_float4(v.x, v.y, ac.x, ac.y);
}

__global__ __launch_bounds__(256) void bin_kernel(
    const int*    __restrict__ nbr,
    const float*  __restrict__ rad,
    const float2* __restrict__ dirs,
    const float*  __restrict__ supp,
    int*          __restrict__ cursor,
    float4*       __restrict__ pay,
    int cap, int nb, int estart, int eend, int E) {
    __shared__ float4 srec[BIN_EDGES];   // 32 KB bucket-sorted 16B records
    __shared__ int lcount[512];          //  2 KB per-bucket counts
    __shared__ int lclaim[512];          //  2 KB claimed global base
    __shared__ int lstart[512];          //  2 KB exclusive scan (LDS position)
    int tid = threadIdx.x;
    for (int k = tid; k < 512; k += 256) lcount[k] = 0;
    __syncthreads();
    int e0 = estart + blockIdx.x * BIN_EDGES + tid;

    // phase 1: stream edges into registers, rank per bucket (no gathers)
    int jj[BIN_EPT]; float qq[BIN_EPT]; v2f dd[BIN_EPT]; int pack[BIN_EPT];
#pragma unroll
    for (int k = 0; k < BIN_EPT; ++k) {
        int e = e0 + k * 256;
        pack[k] = -1; jj[k] = 0; qq[k] = 0.f; dd[k] = (v2f){0.f, 0.f};
        if (e < eend) {
            jj[k] = __builtin_nontemporal_load(nbr + E + e);
            qq[k] = __builtin_nontemporal_load(rad + e);
            dd[k] = __builtin_nontemporal_load((const v2f*)dirs + e);
            int i = __builtin_nontemporal_load(nbr + e);
            int b = i >> PB_SHIFT;
            int r = atomicAdd(&lcount[b], 1);
            pack[k] = (b << 22) | ((i & (PB - 1)) << 12) | r;
        }
    }
    __syncthreads();
    // one global cursor claim per (block,bucket); wave0 scans counts meanwhile
    for (int k = tid; k < nb; k += 256) {
        int c = lcount[k];
        lclaim[k] = c ? atomicAdd(&cursor[(size_t)k * CSTRIDE], c) : 0;
    }
    if (tid < 64) {
        int running = 0;
        for (int c = 0; c < 8; ++c) {
            int orig = lcount[c * 64 + tid];
            int v = orig;
#pragma unroll
            for (int off = 1; off < 64; off <<= 1) {
                int u = __shfl_up(v, off, 64);
                if (tid >= off) v += u;
            }
            lstart[c * 64 + tid] = running + v - orig;
            running += __shfl(v, 63, 64);
        }
    }
    __syncthreads();

    float h  = supp[0];
    float kc = 20.0f * (7.0f / 3.14159265358979323846f) / (h * h * h);

    // phase 2: compute gradient, scatter 16B record into bucket-sorted LDS
#pragma unroll
    for (int k = 0; k < BIN_EPT; ++k) {
        if (pack[k] < 0) continue;
        int b  = pack[k] >> 22;
        int li = (pack[k] >> 12) & (PB - 1);
        int r  = pack[k] & 4095;
        float  q = qq[k];
        v2f    d = dd[k];
        float om  = 1.0f - q;
        float mag = kc * q * om * om * om;
        float gx = -d.x * mag;
        float gy = -d.y * mag;
        int jli  = (jj[k] << 9) | li;
        int cb   = lclaim[b];
        int gi   = (cb + r < cap) ? (b * cap + cb + r) : -1;  // -1: 8-sigma drop
        srec[lstart[b] + r] = make_float4(__int_as_float(jli), gx, gy,
                                          __int_as_float(gi));
    }
    __syncthreads();
    // phase 3: wave-linear writeout -> bucket runs are contiguous, stores
    // coalesce into full sectors (no write-allocate RMW fetch)
    int total = lstart[511] + lcount[511];
    for (int t = tid; t < total; t += 256) {
        float4 rec = srec[t];
        int gi = __float_as_int(rec.w);
        if (gi >= 0) pay[gi] = make_float4(rec.x, rec.y, rec.z, 0.f);
    }
}

__global__ __launch_bounds__(256) void reduce_kernel(
    const float4* __restrict__ pay,
    const int*    __restrict__ cursor, int cap,
    const float4* __restrict__ pre2,
    const float*  __restrict__ dtp,
    float*        __restrict__ partials,
    int spc, int soff, int n) {
    __shared__ float4 stage[TILE];       //  8 KB raw 16B records
    __shared__ float4 sorted[TILE * 2];  // 16 KB expanded 32B records
    __shared__ int    lhist[PB];         //  2 KB counts
    __shared__ int    lofs[PB];          //  2 KB exclusive offsets -> cursors
    int b   = blockIdx.x / spc;
    int s   = blockIdx.x % spc;
    int tid = threadIdx.x;

    // this thread owns particles p0 = base+tid and p1 = base+tid+256
    int p0 = (b << PB_SHIFT) + tid;
    int p1 = p0 + 256;
    float pi0 = (p0 < n) ? pre2[2 * (size_t)p0].x : 0.f;
    float pi1 = (p1 < n) ? pre2[2 * (size_t)p1].x : 0.f;
    float a0[7] = {0.f, 0.f, 0.f, 0.f, 0.f, 0.f, 0.f};
    float a1[7] = {0.f, 0.f, 0.f, 0.f, 0.f, 0.f, 0.f};
    float dt  = dtp[0];
    float dt2 = dt * dt;

    int cnt = cursor[(size_t)b * CSTRIDE];
    if (cnt > cap) cnt = cap;
    int lo = (int)((long long)cnt * s / spc);
    int hi = (int)((long long)cnt * (s + 1) / spc);
    size_t base = (size_t)b * cap;

    for (int T = lo; T < hi; T += TILE) {
        // stage 512 records (512 float4) via DMA
#pragma unroll
        for (int si = 0; si < 2; ++si) {
            int fl  = (si << 8) + tid;
            int rec = T + fl;
            size_t g = (rec < hi) ? (base + rec) : base;
            gload_lds16(pay + g, stage + fl);
        }
        __syncthreads();   // DMA drained + prev-tile readers of lhist/lofs/sorted done
        lhist[tid] = 0; lhist[tid + 256] = 0;
        // read own records, issue pre2[j] gathers EARLY (hide under hist+scan)
        float4 r0 = stage[tid];
        float4 r1 = stage[tid + 256];
        bool v0 = (T + tid) < hi;
        bool v1 = (T + tid + 256) < hi;
        int jli0 = __float_as_int(r0.x);
        int jli1 = __float_as_int(r1.x);
        int li0 = jli0 & (PB - 1);
        int li1 = jli1 & (PB - 1);
        size_t j0 = (size_t)(v0 ? (jli0 >> 9) : 0);
        size_t j1 = (size_t)(v1 ? (jli1 >> 9) : 0);
        float4 ja0 = pre2[2 * j0], jb0 = pre2[2 * j0 + 1];
        float4 ja1 = pre2[2 * j1], jb1 = pre2[2 * j1 + 1];
        __syncthreads();
        // histogram by local particle id (1 int atomic per record)
        if (v0) atomicAdd(&lhist[li0], 1);
        if (v1) atomicAdd(&lhist[li1], 1);
        __syncthreads();
        // exclusive prefix scan of 512 counts by wave 0
        if (tid < 64) {
            int running = 0;
            for (int c = 0; c < 8; ++c) {
                int orig = lhist[c * 64 + tid];
                int v = orig;
#pragma unroll
                for (int off = 1; off < 64; off <<= 1) {
                    int u = __shfl_up(v, off, 64);
                    if (tid >= off) v += u;
                }
                lofs[c * 64 + tid] = running + v - orig;
                running += __shfl(v, 63, 64);
            }
        }
        __syncthreads();
        // scatter: expand to full computed record in particle-sorted order
        if (v0) {
            int slot = atomicAdd(&lofs[li0], 1);
            float c0 = ja0.z * r0.y;                       // aa*gx
            float c1 = ja0.z * r0.z;                       // aa*gy
            float c2 = ja0.w * (r0.y * r0.y + r0.z * r0.z);// aa2m*g2
            float q5 = dt  * (jb0.x * c0 + jb0.y * c1);    // dt*aa*(vj.g)
            float q6 = dt2 * (jb0.z * c0 + jb0.w * c1);    // dt^2*aa*(aj.g)
            sorted[2 * slot]     = make_float4(c0, c1, c2, ja0.y);
            sorted[2 * slot + 1] = make_float4(ja0.x, q5, q6, 0.f);
        }
        if (v1) {
            int slot = atomicAdd(&lofs[li1], 1);
            float c0 = ja1.z * r1.y;
            float c1 = ja1.z * r1.z;
            float c2 = ja1.w * (r1.y * r1.y + r1.z * r1.z);
            float q5 = dt  * (jb1.x * c0 + jb1.y * c1);
            float q6 = dt2 * (jb1.z * c0 + jb1.w * c1);
            sorted[2 * slot]     = make_float4(c0, c1, c2, ja1.y);
            sorted[2 * slot + 1] = make_float4(ja1.x, q5, q6, 0.f);
        }
        __syncthreads();
        // register gather: contiguous segment per particle, NO atomics
        {
            int end0 = lofs[tid];
            for (int r = end0 - lhist[tid]; r < end0; ++r) {
                float4 e0 = sorted[2 * r];
                float4 e1 = sorted[2 * r + 1];
                float rc = -(pi0 + e1.x) * e0.w;
                a0[0] += e0.x; a0[1] += e0.y; a0[2] += e0.z;
                a0[3] += rc * e0.x; a0[4] += rc * e0.y;
                a0[5] += e1.y; a0[6] += e1.z;
            }
            int end1 = lofs[tid + 256];
            for (int r = end1 - lhist[tid + 256]; r < end1; ++r) {
                float4 e0 = sorted[2 * r];
                float4 e1 = sorted[2 * r + 1];
                float rc = -(pi1 + e1.x) * e0.w;
                a1[0] += e0.x; a1[1] += e0.y; a1[2] += e0.z;
                a1[3] += rc * e0.x; a1[4] += rc * e0.y;
                a1[5] += e1.y; a1[6] += e1.z;
            }
        }
        // loop-top sync protects stage/lhist/lofs/sorted
    }

    // epilogue: apply linear i-side corrections, write slice from registers
    float* dst = partials + ((size_t)b * SLICES + soff + s) * (PB * 7);
    {
        float4 va = (p0 < n) ? pre2[2 * (size_t)p0 + 1]
                             : make_float4(0.f, 0.f, 0.f, 0.f);
        float src = a0[5] - dt  * (va.x * a0[0] + va.y * a0[1]);
        float ker = dt2 * (va.z * a0[0] + va.w * a0[1]) - a0[6];
        float* d = dst + (size_t)tid * 7;
        d[0] = a0[0]; d[1] = a0[1]; d[2] = a0[2]; d[3] = a0[3]; d[4] = a0[4];
        d[5] = src;   d[6] = ker;
    }
    {
        float4 va = (p1 < n) ? pre2[2 * (size_t)p1 + 1]
                             : make_float4(0.f, 0.f, 0.f, 0.f);
        float src = a1[5] - dt  * (va.x * a1[0] + va.y * a1[1]);
        float ker = dt2 * (va.z * a1[0] + va.w * a1[1]) - a1[6];
        float* d = dst + (size_t)(tid + 256) * 7;
        d[0] = a1[0]; d[1] = a1[1]; d[2] = a1[2]; d[3] = a1[3]; d[4] = a1[4];
        d[5] = src;   d[6] = ker;
    }
}

// ---- fallback: direct global float atomics ----
__global__ void edge_kernel(const int* __restrict__ nbr,
                            const float* __restrict__ rad,
                            const float2* __restrict__ dirs,
                            const float4* __restrict__ pre2,
                            const float* __restrict__ supp,
                            const float* __restrict__ dtp,
                            float* __restrict__ acc, int E) {
    int e = blockIdx.x * blockDim.x + threadIdx.x;
    if (e >= E) return;
    float h = supp[0], dt = dtp[0];
    float kc = 20.0f * (7.0f / 3.14159265358979323846f) / (h * h * h);
    int i = nbr[e];
    int j = nbr[E + e];
    float  q = rad[e];
    float2 d = dirs[e];
    float om  = 1.0f - q;
    float mag = kc * q * om * om * om;
    float gx = -d.x * mag;
    float gy = -d.y * mag;
    float g2 = gx * gx + gy * gy;
    float4 ja = pre2[2 * (size_t)j];      // {p, r, aa, aa2m}
    float4 jb = pre2[2 * (size_t)j + 1];
    float4 ia = pre2[2 * (size_t)i];
    float4 ib = pre2[2 * (size_t)i + 1];
    float aaj = ja.z;
    float m   = ja.y * aaj;
    float pp  = -m * (ia.x + ja.x);
    float vdotg = (ib.x - jb.x) * gx + (ib.y - jb.y) * gy;
    float adotg = (ib.z - jb.z) * gx + (ib.w - jb.w) * gy;
    float* base = acc + (size_t)i * 8;
    atomicAdd(base + 0, aaj * gx);
    atomicAdd(base + 1, aaj * gy);
    atomicAdd(base + 2, ja.w * g2);
    atomicAdd(base + 3, pp * gx);
    atomicAdd(base + 4, pp * gy);
    atomicAdd(base + 5, -dt * aaj * vdotg);
    atomicAdd(base + 6, dt * dt * aaj * adotg);
}

__global__ __launch_bounds__(256) void fin_kernel(
    const float* __restrict__ area,
    const float* __restrict__ actualArea,
    const float* __restrict__ restDensity,
    const float* __restrict__ dtp,
    const float* __restrict__ data, int mode,
    float* __restrict__ out, int n) {
    int t = blockIdx.x * blockDim.x + threadIdx.x;
    if (t >= n) return;
    float s0 = 0, s1 = 0, s2 = 0, s3 = 0, s4 = 0, s5 = 0, s6 = 0;
    if (mode == 0) {
        const float* base = data + ((size_t)(t >> PB_SHIFT) * SLICES) * (PB * 7)
                                 + (size_t)(t & (PB - 1)) * 7;
#pragma unroll
        for (int s = 0; s < SLICES; ++s) {
            const float* p = base + (size_t)s * (PB * 7);
            s0 += p[0]; s1 += p[1]; s2 += p[2]; s3 += p[3];
            s4 += p[4]; s5 += p[5]; s6 += p[6];
        }
    } else {
        const float* a = data + (size_t)t * 8;
        s0 = a[0]; s1 = a[1]; s2 = a[2]; s3 = a[3];
        s4 = a[4]; s5 = a[5]; s6 = a[6];
    }
    float dt   = dtp[0];
    float fac  = -dt * dt * actualArea[t];
    float mass = area[t] * restDensity[t];
    float alpha = fac / mass * (s0 * s0 + s1 * s1) + fac * s2;
    float* o = out + (size_t)t * 5;
    o[0] = alpha;
    o[1] = s3;
    o[2] = s4;
    o[3] = s5;
    o[4] = s6;
}

extern "C" void kernel_launch(void* const* d_in, const int* in_sizes, int n_in,
                              void* d_out, int out_size, void* d_ws, size_t ws_size,
                              hipStream_t stream) {
    const float* area        = (const float*)d_in[0];
    const float* actualArea  = (const float*)d_in[1];
    const float* restDensity = (const float*)d_in[2];
    const float* density     = (const float*)d_in[3];
    const float* pressure2   = (const float*)d_in[4];
    const float2* vel        = (const float2*)d_in[5];
    const float2* accel      = (const float2*)d_in[6];
    const float* rad         = (const float*)d_in[7];
    const float2* dirs       = (const float2*)d_in[8];
    const int*   nbr         = (const int*)d_in[9];
    const float* supp        = (const float*)d_in[10];
    const float* dtp         = (const float*)d_in[11];
    float* out = (float*)d_out;

    int N = in_sizes[0];
    int E = in_sizes[7];
    int nb = (N + PB - 1) >> PB_SHIFT;   // 512 for N=262144

    size_t sz_cur   = (size_t)nb * CSTRIDE * 8 * sizeof(int);
    size_t off_pre  = align256(sz_cur);
    size_t sz_pre   = (size_t)N * 8 * sizeof(float);
    size_t off_part = align256(off_pre + sz_pre);
    size_t sz_part  = (size_t)nb * SLICES * PB * 7 * sizeof(float);
    size_t off_pay  = align256(off_part + sz_part);

    int* cursor     = (int*)d_ws;
    float4* pre2    = (float4*)((char*)d_ws + off_pre);
    float* partials = (float*)((char*)d_ws + off_part);

    // pick chunking so payload fits (one 16B record/edge, bucket-grouped)
    int nchunk = 0, cap = 0;
    if (nb <= 512 && ws_size > off_pay) {
        for (int c = 1; c <= 8; c *= 2) {
            long long Ec = (E + c - 1) / c;
            double mean = (double)Ec / (double)nb;
            long long need = (long long)(mean + 8.0 * sqrt(mean) + 128.0);
            need = (need + 63) & ~63ll;
            if (off_pay + (size_t)nb * need * 16 <= ws_size) {
                nchunk = c; cap = (int)need; break;
            }
        }
    }

    int bs = 256;
    int grid_n = (N + bs - 1) / bs;
    if (nchunk > 0) {
        float4* pay = (float4*)((char*)d_ws + off_pay);
        int ncursor = nb * CSTRIDE * nchunk;
        pre_kernel<<<grid_n, bs, 0, stream>>>(
            area, actualArea, restDensity, density, pressure2, vel, accel,
            pre2, cursor, ncursor, (float*)nullptr, 0, N);
        int spc = SLICES / nchunk; if (spc < 1) spc = 1;
        int Ec  = (E + nchunk - 1) / nchunk;
        for (int c = 0; c < nchunk; ++c) {
            int es = c * Ec;
            int ee = es + Ec; if (ee > E) ee = E;
            if (es >= ee) break;
            int* curC = cursor + (size_t)c * nb * CSTRIDE;
            int nblk = (ee - es + BIN_EDGES - 1) / BIN_EDGES;
            bin_kernel<<<nblk, bs, 0, stream>>>(
                nbr, rad, dirs, supp, curC, pay, cap, nb, es, ee, E);
            reduce_kernel<<<nb * spc, bs, 0, stream>>>(
                pay, curC, cap, pre2, dtp, partials, spc, c * spc, N);
        }
        fin_kernel<<<grid_n, bs, 0, stream>>>(
            area, actualArea, restDensity, dtp, partials, 0, out, N);
    } else {
        float* acc = partials;  // [N,8] at off_part
        pre_kernel<<<grid_n, bs, 0, stream>>>(
            area, actualArea, restDensity, density, pressure2, vel, accel,
            pre2, cursor, 0, acc, N * 8, N);
        edge_kernel<<<(E + bs - 1) / bs, bs, 0, stream>>>(
            nbr, rad, dirs, pre2, supp, dtp, acc, E);
        fin_kernel<<<grid_n, bs, 0, stream>>>(
            area, actualArea, restDensity, dtp, acc, 1, out, N);
    }
}